// Round 1
// baseline (456.013 us; speedup 1.0000x reference)
//
#include <hip/hip_runtime.h>

// LoRA MLP: out = silu_mul(x@(Wgu + Agu@Bgu)) @ (Wd + Ad@Bd)
// T=16384, D_MODEL=1024, D_FF=2816 (2*D_FF=5632), RANK=16
//
// Plan:
//   prep_weff: W_eff = W + A@B (fp32), stored TRANSPOSED as bf16 -> NT GEMM
//   conv_bf16: x fp32 -> bf16
//   gemm1: h = silu(x@Wgu_eff[:, :2816]) * (x@Wgu_eff[:, 2816:])  (dual-acc tile)
//   gemm2: out = h @ Wd_eff
// Workspace layout (bytes):
//   [0,            11534336)  Wgu_t  bf16 [5632][1024]
//   [11534336,     17301504)  Wd_t   bf16 [1024][2816]
//   [17301504,     50855936)  x_bf16      [16384][1024]
//   [50855936,    143130624)  h_bf16      [16384][2816]

typedef __bf16 bf16_t;
typedef __bf16 bf16x4 __attribute__((ext_vector_type(4)));
typedef __bf16 bf16x8 __attribute__((ext_vector_type(8)));
typedef float f32x4 __attribute__((ext_vector_type(4)));

#define TOKENS 16384
#define DMODEL 1024
#define DFF    2816
#define N2F    5632

__device__ __forceinline__ void gload16(const void* g, void* l) {
    __builtin_amdgcn_global_load_lds(
        (const __attribute__((address_space(1))) void*)g,
        (__attribute__((address_space(3))) void*)l, 16, 0, 0);
}

// ---------------------------------------------------------------------------
// W_eff_t[n][k] = bf16( W[k][n] + sum_r A[k][r]*B[r][n] )   (fp32 math)
// block: 256 threads, tile 64(k) x 64(n)
template<int KTOT, int NTOT>
__global__ __launch_bounds__(256) void prep_weff(
        const float* __restrict__ W, const float* __restrict__ A,
        const float* __restrict__ B, bf16_t* __restrict__ Wt) {
    __shared__ float Ws[64][65];
    __shared__ float As[64][17];
    __shared__ float Bs[16][64];
    const int t = threadIdx.x;
    const int k0 = blockIdx.x * 64, n0 = blockIdx.y * 64;
    #pragma unroll
    for (int i = 0; i < 16; ++i) {
        int row = i * 4 + t / 64, col = t % 64;
        Ws[row][col] = W[(size_t)(k0 + row) * NTOT + n0 + col];
    }
    #pragma unroll
    for (int i = 0; i < 4; ++i) {
        int idx = i * 256 + t;
        As[idx / 16][idx % 16] = A[(size_t)(k0 + idx / 16) * 16 + idx % 16];
    }
    #pragma unroll
    for (int i = 0; i < 4; ++i) {
        int idx = i * 256 + t;
        Bs[idx / 64][idx % 64] = B[(size_t)(idx / 64) * NTOT + n0 + idx % 64];
    }
    __syncthreads();
    const int kl = t % 64;
    #pragma unroll
    for (int j = 0; j < 16; ++j) {
        int nl = j * 4 + t / 64;
        float val = Ws[kl][nl];
        #pragma unroll
        for (int r = 0; r < 16; ++r) val += As[kl][r] * Bs[r][nl];
        Wt[(size_t)(n0 + nl) * KTOT + k0 + kl] = (bf16_t)val;
    }
}

// ---------------------------------------------------------------------------
__global__ __launch_bounds__(256) void conv_bf16(
        const float* __restrict__ in, bf16_t* __restrict__ out, int n4) {
    int i = blockIdx.x * 256 + threadIdx.x;
    if (i < n4) {
        float4 v = ((const float4*)in)[i];
        bf16x4 o;
        o.x = (bf16_t)v.x; o.y = (bf16_t)v.y; o.z = (bf16_t)v.z; o.w = (bf16_t)v.w;
        ((bf16x4*)out)[i] = o;
    }
}

// ---------------------------------------------------------------------------
// GEMM1: h[T][DFF] = silu(g)*u where [g|u] = X[T][1024] @ Wgu_t^T
// tile: BM=128 x BF=64, BK=64. 4 waves in 2x2; each wave 64x32 dual (gate+up).
__global__ __launch_bounds__(256) void gemm1(
        const bf16_t* __restrict__ X, const bf16_t* __restrict__ Wt,
        bf16_t* __restrict__ H) {
    __shared__ bf16_t As[128 * 64];
    __shared__ bf16_t Bgs[64 * 64];
    __shared__ bf16_t Bus[64 * 64];
    const int t = threadIdx.x, l = t & 63, w = t >> 6;
    const int wr = w >> 1, wc = w & 1;
    const int mbase = blockIdx.y * 128;
    const int fbase = blockIdx.x * 64;
    const int lrow = l >> 3, lcol8 = (l & 7) * 8;
    const int l15 = l & 15, lhi = l >> 4;
    f32x4 accg[4][2] = {};
    f32x4 accu[4][2] = {};
    for (int kt = 0; kt < 16; ++kt) {
        const int k0 = kt * 64;
        #pragma unroll
        for (int i = 0; i < 4; ++i) {
            int c = w * 4 + i;
            gload16(X + (size_t)(mbase + c * 8 + lrow) * DMODEL + k0 + lcol8,
                    As + c * 512);
        }
        #pragma unroll
        for (int i = 0; i < 2; ++i) {
            int c = w * 2 + i;
            gload16(Wt + (size_t)(fbase + c * 8 + lrow) * DMODEL + k0 + lcol8,
                    Bgs + c * 512);
            gload16(Wt + (size_t)(fbase + DFF + c * 8 + lrow) * DMODEL + k0 + lcol8,
                    Bus + c * 512);
        }
        asm volatile("s_waitcnt vmcnt(0)" ::: "memory");
        __syncthreads();
        #pragma unroll
        for (int ks = 0; ks < 2; ++ks) {
            bf16x8 a[4], bg[2], bu[2];
            const int koff = ks * 32 + lhi * 8;
            #pragma unroll
            for (int m = 0; m < 4; ++m)
                a[m] = *(const bf16x8*)(As + (wr * 64 + m * 16 + l15) * 64 + koff);
            #pragma unroll
            for (int n = 0; n < 2; ++n) {
                bg[n] = *(const bf16x8*)(Bgs + (wc * 32 + n * 16 + l15) * 64 + koff);
                bu[n] = *(const bf16x8*)(Bus + (wc * 32 + n * 16 + l15) * 64 + koff);
            }
            #pragma unroll
            for (int m = 0; m < 4; ++m)
                #pragma unroll
                for (int n = 0; n < 2; ++n) {
                    accg[m][n] = __builtin_amdgcn_mfma_f32_16x16x32_bf16(
                        a[m], bg[n], accg[m][n], 0, 0, 0);
                    accu[m][n] = __builtin_amdgcn_mfma_f32_16x16x32_bf16(
                        a[m], bu[n], accu[m][n], 0, 0, 0);
                }
        }
        __syncthreads();
    }
    // epilogue: silu(g)*u -> bf16
    #pragma unroll
    for (int m = 0; m < 4; ++m)
        #pragma unroll
        for (int n = 0; n < 2; ++n)
            #pragma unroll
            for (int r = 0; r < 4; ++r) {
                int grow = mbase + wr * 64 + m * 16 + lhi * 4 + r;
                int gcol = fbase + wc * 32 + n * 16 + l15;
                float g = accg[m][n][r], u = accu[m][n][r];
                float hv = g / (1.0f + __expf(-g)) * u;
                H[(size_t)grow * DFF + gcol] = (bf16_t)hv;
            }
}

// ---------------------------------------------------------------------------
// GEMM2: out[T][1024] = H[T][2816] @ Wd_t^T   (fp32 out)
// tile: 128x128, BK=64, 4 waves each 64x64
__global__ __launch_bounds__(256) void gemm2(
        const bf16_t* __restrict__ H, const bf16_t* __restrict__ Wt,
        float* __restrict__ O) {
    __shared__ bf16_t As[128 * 64];
    __shared__ bf16_t Bs[128 * 64];
    const int t = threadIdx.x, l = t & 63, w = t >> 6;
    const int wr = w >> 1, wc = w & 1;
    const int mbase = blockIdx.y * 128;
    const int nbase = blockIdx.x * 128;
    const int lrow = l >> 3, lcol8 = (l & 7) * 8;
    const int l15 = l & 15, lhi = l >> 4;
    f32x4 acc[4][4] = {};
    for (int kt = 0; kt < 44; ++kt) {
        const int k0 = kt * 64;
        #pragma unroll
        for (int i = 0; i < 4; ++i) {
            int c = w * 4 + i;
            gload16(H + (size_t)(mbase + c * 8 + lrow) * DFF + k0 + lcol8,
                    As + c * 512);
            gload16(Wt + (size_t)(nbase + c * 8 + lrow) * DFF + k0 + lcol8,
                    Bs + c * 512);
        }
        asm volatile("s_waitcnt vmcnt(0)" ::: "memory");
        __syncthreads();
        #pragma unroll
        for (int ks = 0; ks < 2; ++ks) {
            bf16x8 a[4], b[4];
            const int koff = ks * 32 + lhi * 8;
            #pragma unroll
            for (int m = 0; m < 4; ++m)
                a[m] = *(const bf16x8*)(As + (wr * 64 + m * 16 + l15) * 64 + koff);
            #pragma unroll
            for (int n = 0; n < 4; ++n)
                b[n] = *(const bf16x8*)(Bs + (wc * 64 + n * 16 + l15) * 64 + koff);
            #pragma unroll
            for (int m = 0; m < 4; ++m)
                #pragma unroll
                for (int n = 0; n < 4; ++n)
                    acc[m][n] = __builtin_amdgcn_mfma_f32_16x16x32_bf16(
                        a[m], b[n], acc[m][n], 0, 0, 0);
        }
        __syncthreads();
    }
    #pragma unroll
    for (int m = 0; m < 4; ++m)
        #pragma unroll
        for (int n = 0; n < 4; ++n)
            #pragma unroll
            for (int r = 0; r < 4; ++r) {
                int grow = mbase + wr * 64 + m * 16 + lhi * 4 + r;
                int gcol = nbase + wc * 64 + n * 16 + l15;
                O[(size_t)grow * DMODEL + gcol] = acc[m][n][r];
            }
}

// ---------------------------------------------------------------------------
extern "C" void kernel_launch(void* const* d_in, const int* in_sizes, int n_in,
                              void* d_out, int out_size, void* d_ws, size_t ws_size,
                              hipStream_t stream) {
    const float* x   = (const float*)d_in[0];
    const float* Wgu = (const float*)d_in[1];
    const float* Agu = (const float*)d_in[2];
    const float* Bgu = (const float*)d_in[3];
    const float* Wd  = (const float*)d_in[4];
    const float* Ad  = (const float*)d_in[5];
    const float* Bd  = (const float*)d_in[6];
    float* out = (float*)d_out;
    char* ws = (char*)d_ws;

    bf16_t* wgut = (bf16_t*)(ws);                    // [5632][1024]
    bf16_t* wdt  = (bf16_t*)(ws + 11534336);         // [1024][2816]
    bf16_t* xb   = (bf16_t*)(ws + 17301504);         // [16384][1024]
    bf16_t* hb   = (bf16_t*)(ws + 50855936);         // [16384][2816]

    prep_weff<DMODEL, N2F><<<dim3(DMODEL / 64, N2F / 64), 256, 0, stream>>>(
        Wgu, Agu, Bgu, wgut);
    prep_weff<DFF, DMODEL><<<dim3(DFF / 64, DMODEL / 64), 256, 0, stream>>>(
        Wd, Ad, Bd, wdt);
    conv_bf16<<<(TOKENS * DMODEL / 4) / 256, 256, 0, stream>>>(
        x, xb, TOKENS * DMODEL / 4);
    gemm1<<<dim3(DFF / 64, TOKENS / 128), 256, 0, stream>>>(xb, wgut, hb);
    gemm2<<<dim3(DMODEL / 128, TOKENS / 128), 256, 0, stream>>>(hb, wdt, out);
}

// Round 2
// 364.723 us; speedup vs baseline: 1.2503x; 1.2503x over previous
//
#include <hip/hip_runtime.h>

// LoRA MLP: out = silu_mul(x@(Wgu + Agu@Bgu)) @ (Wd + Ad@Bd)
// T=16384, D_MODEL=1024, D_FF=2816 (2*D_FF=5632), RANK=16
//
// R2: 256-wide 8-phase pipelined GEMMs (T3+T4 counted vmcnt, T5 setprio,
// K-split LDS slots [256][32] @64B stride = bank-conflict-free ds_read_b128).
//
// Workspace layout (bytes):
//   [0,            11534336)  Wgu_t  bf16 [5632][1024]
//   [11534336,     17301504)  Wd_t   bf16 [1024][2816]
//   [17301504,     50855936)  x_bf16      [16384][1024]
//   [50855936,    143130624)  h_bf16      [16384][2816]

typedef __bf16 bf16_t;
typedef __bf16 bf16x4 __attribute__((ext_vector_type(4)));
typedef __bf16 bf16x8 __attribute__((ext_vector_type(8)));
typedef float f32x4 __attribute__((ext_vector_type(4)));

#define TOKENS 16384
#define DMODEL 1024
#define DFF    2816
#define N2F    5632

#define DSB() __builtin_amdgcn_sched_barrier(0)
#define BAR() __builtin_amdgcn_s_barrier()
#define LGKM0() do { asm volatile("s_waitcnt lgkmcnt(0)" ::: "memory"); \
                     __builtin_amdgcn_sched_barrier(0); } while (0)
#define VMW(n) do { asm volatile("s_waitcnt vmcnt(" #n ")" ::: "memory"); \
                    __builtin_amdgcn_sched_barrier(0); } while (0)
#define MFMA(d, va, vb) d = __builtin_amdgcn_mfma_f32_16x16x32_bf16(va, vb, d, 0, 0, 0)

__device__ __forceinline__ void gload16(const bf16_t* g, bf16_t* l) {
    __builtin_amdgcn_global_load_lds(
        (const __attribute__((address_space(1))) void*)g,
        (__attribute__((address_space(3))) void*)l, 16, 0, 0);
}

// ---------------------------------------------------------------------------
// W_eff_t[n][k] = bf16( W[k][n] + sum_r A[k][r]*B[r][n] )   (fp32 math)
template<int KTOT, int NTOT>
__global__ __launch_bounds__(256) void prep_weff(
        const float* __restrict__ W, const float* __restrict__ A,
        const float* __restrict__ B, bf16_t* __restrict__ Wt) {
    __shared__ float Ws[64][65];
    __shared__ float As[64][17];
    __shared__ float Bs[16][64];
    const int t = threadIdx.x;
    const int k0 = blockIdx.x * 64, n0 = blockIdx.y * 64;
    #pragma unroll
    for (int i = 0; i < 16; ++i) {
        int row = i * 4 + t / 64, col = t % 64;
        Ws[row][col] = W[(size_t)(k0 + row) * NTOT + n0 + col];
    }
    #pragma unroll
    for (int i = 0; i < 4; ++i) {
        int idx = i * 256 + t;
        As[idx / 16][idx % 16] = A[(size_t)(k0 + idx / 16) * 16 + idx % 16];
    }
    #pragma unroll
    for (int i = 0; i < 4; ++i) {
        int idx = i * 256 + t;
        Bs[idx / 64][idx % 64] = B[(size_t)(idx / 64) * NTOT + n0 + idx % 64];
    }
    __syncthreads();
    const int kl = t % 64;
    #pragma unroll
    for (int j = 0; j < 16; ++j) {
        int nl = j * 4 + t / 64;
        float val = Ws[kl][nl];
        #pragma unroll
        for (int r = 0; r < 16; ++r) val += As[kl][r] * Bs[r][nl];
        Wt[(size_t)(n0 + nl) * KTOT + k0 + kl] = (bf16_t)val;
    }
}

// ---------------------------------------------------------------------------
__global__ __launch_bounds__(256) void conv_bf16(
        const float* __restrict__ in, bf16_t* __restrict__ out, int n4) {
    int i = blockIdx.x * 256 + threadIdx.x;
    if (i < n4) {
        float4 v = ((const float4*)in)[i];
        bf16x4 o;
        o.x = (bf16_t)v.x; o.y = (bf16_t)v.y; o.z = (bf16_t)v.z; o.w = (bf16_t)v.w;
        ((bf16x4*)out)[i] = o;
    }
}

// ---------------------------------------------------------------------------
// GEMM1: h[T][DFF] = silu(g)*u, [g|u] = X[T][1024] @ Wgu_t^T
// Tile 256(M) x 128(F) dual gate/up, BK=64, 8 waves (2Mx4F), 8-phase pipe.
// LDS (bf16 elems): buf b at b*32768; A-ks0 @0, A-ks1 @8192,
//                   B-ks0 @16384, B-ks1 @24576. Slot = [256 rows][32 cols].
// B slot rows 0-127 = gate rows (fbase+..), 128-255 = up rows (DFF+fbase+..).
__global__ __launch_bounds__(512, 2) void gemm1(
        const bf16_t* __restrict__ X, const bf16_t* __restrict__ Wt,
        bf16_t* __restrict__ H) {
    __shared__ bf16_t lds[65536];
    const int t = threadIdx.x, l = t & 63;
    const int wid = t >> 6, wr = wid >> 2, wc = wid & 3;
    const int l15 = l & 15, lhi = l >> 4;
    const int wg = ((int)blockIdx.x & 7) * 176 + ((int)blockIdx.x >> 3);
    const int tf = wg >> 6, tm = wg & 63;          // 22 f-tiles x 64 m-tiles
    const int mbase = tm * 256, fbase = tf * 128;
    const int srow = t >> 2, sc8 = (t & 3) * 8;
    const bf16_t* gA  = X  + (size_t)(mbase + srow) * DMODEL + sc8;
    const bf16_t* gBg = Wt + (size_t)(fbase + srow) * DMODEL + sc8;
    const bf16_t* gBu = Wt + (size_t)(DFF + fbase + srow) * DMODEL + sc8;
    bf16_t* sdA = lds + wid * 512;
    bf16_t* sdB = lds + 16384 + wid * 512;
    const int aoff = (wr * 128 + l15) * 32 + lhi * 8;
    const int boff = 16384 + (wc * 32 + l15) * 32 + lhi * 8;

    f32x4 accg[8][2] = {}, accu[8][2] = {};
    bf16x8 a[4], bg[2], bu[2];

#define G1_STAGE_A(kt, ks, buf) do { const int kc = (kt) * 64 + (ks) * 32;        \
    gload16(gA + kc, sdA + (buf) * 32768 + (ks) * 8192);                          \
    gload16(gA + (size_t)128 * DMODEL + kc,                                       \
            sdA + (buf) * 32768 + (ks) * 8192 + 4096); } while (0)
#define G1_STAGE_B(kt, ks, buf) do { const int kc = (kt) * 64 + (ks) * 32;        \
    gload16(gBg + kc, sdB + (buf) * 32768 + (ks) * 8192);                         \
    gload16(gBu + kc, sdB + (buf) * 32768 + (ks) * 8192 + 4096); } while (0)
#define G1_READ_A(mh, ks, cur) do {                                               \
    const bf16_t* p = lds + (cur) * 32768 + (ks) * 8192 + (mh) * 2048 + aoff;     \
    a[0] = *(const bf16x8*)(p);        a[1] = *(const bf16x8*)(p + 512);          \
    a[2] = *(const bf16x8*)(p + 1024); a[3] = *(const bf16x8*)(p + 1536); } while (0)
#define G1_READ_B(ks, cur) do {                                                   \
    const bf16_t* p = lds + (cur) * 32768 + (ks) * 8192 + boff;                   \
    bg[0] = *(const bf16x8*)(p);        bg[1] = *(const bf16x8*)(p + 512);        \
    bu[0] = *(const bf16x8*)(p + 4096); bu[1] = *(const bf16x8*)(p + 4608); } while (0)
#define G1_MFMA(mh) do { __builtin_amdgcn_s_setprio(1);                           \
    _Pragma("unroll")                                                             \
    for (int i = 0; i < 4; ++i) {                                                 \
        MFMA(accg[(mh) * 4 + i][0], a[i], bg[0]);                                 \
        MFMA(accu[(mh) * 4 + i][0], a[i], bu[0]);                                 \
        MFMA(accg[(mh) * 4 + i][1], a[i], bg[1]);                                 \
        MFMA(accu[(mh) * 4 + i][1], a[i], bu[1]);                                 \
    }                                                                             \
    __builtin_amdgcn_s_setprio(0); } while (0)

    // prologue: tile0 all 4 slots, tile1 {B0, A0, B1}; wait tile0, barrier
    G1_STAGE_A(0, 0, 0); G1_STAGE_B(0, 0, 0); G1_STAGE_A(0, 1, 0); G1_STAGE_B(0, 1, 0);
    G1_STAGE_B(1, 0, 1); G1_STAGE_A(1, 0, 1); G1_STAGE_B(1, 1, 1);
    VMW(6); BAR(); DSB();

    const int NT = DMODEL / 64;  // 16
    for (int kt = 0; kt < NT; ++kt) {
        const int cur = kt & 1, nxt = cur ^ 1;
        // P1: a(mh0,ks0)+b(ks0); issue A-ks1(kt+1)->nxt
        G1_READ_A(0, 0, cur); G1_READ_B(0, cur);
        if (kt + 1 < NT) G1_STAGE_A(kt + 1, 1, nxt);
        DSB(); BAR(); LGKM0();
        G1_MFMA(0);
        DSB(); BAR(); DSB();
        // P2: a(mh1,ks0); issue B-ks0(kt+2)->cur
        G1_READ_A(1, 0, cur);
        if (kt + 2 < NT) G1_STAGE_B(kt + 2, 0, cur);
        DSB(); BAR(); LGKM0();
        G1_MFMA(1);
        DSB(); BAR(); DSB();
        // P3: a(mh0,ks1)+b(ks1); issue A-ks0(kt+2)->cur
        G1_READ_A(0, 1, cur); G1_READ_B(1, cur);
        if (kt + 2 < NT) G1_STAGE_A(kt + 2, 0, cur);
        DSB(); BAR(); LGKM0();
        G1_MFMA(0);
        DSB(); BAR(); DSB();
        // P4: a(mh1,ks1); issue B-ks1(kt+2)->cur; counted vmcnt
        G1_READ_A(1, 1, cur);
        if (kt + 2 < NT) G1_STAGE_B(kt + 2, 1, cur);
        if (kt + 2 < NT) { VMW(6); } else { VMW(0); }
        DSB(); BAR(); LGKM0();
        G1_MFMA(1);
        DSB(); BAR(); DSB();
    }
#undef G1_STAGE_A
#undef G1_STAGE_B
#undef G1_READ_A
#undef G1_READ_B
#undef G1_MFMA

    #pragma unroll
    for (int m = 0; m < 8; ++m)
        #pragma unroll
        for (int n = 0; n < 2; ++n)
            #pragma unroll
            for (int r = 0; r < 4; ++r) {
                int row = mbase + wr * 128 + m * 16 + lhi * 4 + r;
                int col = fbase + wc * 32 + n * 16 + l15;
                float g = accg[m][n][r], u = accu[m][n][r];
                H[(size_t)row * DFF + col] = (bf16_t)(g / (1.0f + __expf(-g)) * u);
            }
}

// ---------------------------------------------------------------------------
// GEMM2: out[T][1024] = H[T][2816] @ Wd_t^T   (fp32 out)
// Tile 256x256, BK=64, 8 waves (2Mx4N), same 8-phase pipe.
__global__ __launch_bounds__(512, 2) void gemm2(
        const bf16_t* __restrict__ Hm, const bf16_t* __restrict__ Wt,
        float* __restrict__ O) {
    __shared__ bf16_t lds[65536];
    const int t = threadIdx.x, l = t & 63;
    const int wid = t >> 6, wr = wid >> 2, wc = wid & 3;
    const int l15 = l & 15, lhi = l >> 4;
    const int wg = ((int)blockIdx.x & 7) * 32 + ((int)blockIdx.x >> 3);
    const int tn = wg >> 6, tm = wg & 63;          // 4 n-tiles x 64 m-tiles
    const int mbase = tm * 256, nbase = tn * 256;
    const int srow = t >> 2, sc8 = (t & 3) * 8;
    const bf16_t* gA = Hm + (size_t)(mbase + srow) * DFF + sc8;
    const bf16_t* gB = Wt + (size_t)(nbase + srow) * DFF + sc8;
    bf16_t* sdA = lds + wid * 512;
    bf16_t* sdB = lds + 16384 + wid * 512;
    const int aoff = (wr * 128 + l15) * 32 + lhi * 8;
    const int boff = 16384 + (wc * 64 + l15) * 32 + lhi * 8;

    f32x4 acc[8][4] = {};
    bf16x8 a[4], b[4];

#define G2_STAGE_A(kt, ks, buf) do { const int kc = (kt) * 64 + (ks) * 32;        \
    gload16(gA + kc, sdA + (buf) * 32768 + (ks) * 8192);                          \
    gload16(gA + (size_t)128 * DFF + kc,                                          \
            sdA + (buf) * 32768 + (ks) * 8192 + 4096); } while (0)
#define G2_STAGE_B(kt, ks, buf) do { const int kc = (kt) * 64 + (ks) * 32;        \
    gload16(gB + kc, sdB + (buf) * 32768 + (ks) * 8192);                          \
    gload16(gB + (size_t)128 * DFF + kc,                                          \
            sdB + (buf) * 32768 + (ks) * 8192 + 4096); } while (0)
#define G2_READ_A(mh, ks, cur) do {                                               \
    const bf16_t* p = lds + (cur) * 32768 + (ks) * 8192 + (mh) * 2048 + aoff;     \
    a[0] = *(const bf16x8*)(p);        a[1] = *(const bf16x8*)(p + 512);          \
    a[2] = *(const bf16x8*)(p + 1024); a[3] = *(const bf16x8*)(p + 1536); } while (0)
#define G2_READ_B(ks, cur) do {                                                   \
    const bf16_t* p = lds + (cur) * 32768 + (ks) * 8192 + boff;                   \
    b[0] = *(const bf16x8*)(p);        b[1] = *(const bf16x8*)(p + 512);          \
    b[2] = *(const bf16x8*)(p + 1024); b[3] = *(const bf16x8*)(p + 1536); } while (0)
#define G2_MFMA(mh) do { __builtin_amdgcn_s_setprio(1);                           \
    _Pragma("unroll")                                                             \
    for (int i = 0; i < 4; ++i) {                                                 \
        MFMA(acc[(mh) * 4 + i][0], a[i], b[0]);                                   \
        MFMA(acc[(mh) * 4 + i][1], a[i], b[1]);                                   \
        MFMA(acc[(mh) * 4 + i][2], a[i], b[2]);                                   \
        MFMA(acc[(mh) * 4 + i][3], a[i], b[3]);                                   \
    }                                                                             \
    __builtin_amdgcn_s_setprio(0); } while (0)

    G2_STAGE_A(0, 0, 0); G2_STAGE_B(0, 0, 0); G2_STAGE_A(0, 1, 0); G2_STAGE_B(0, 1, 0);
    G2_STAGE_B(1, 0, 1); G2_STAGE_A(1, 0, 1); G2_STAGE_B(1, 1, 1);
    VMW(6); BAR(); DSB();

    const int NT = DFF / 64;  // 44
    for (int kt = 0; kt < NT; ++kt) {
        const int cur = kt & 1, nxt = cur ^ 1;
        G2_READ_A(0, 0, cur); G2_READ_B(0, cur);
        if (kt + 1 < NT) G2_STAGE_A(kt + 1, 1, nxt);
        DSB(); BAR(); LGKM0();
        G2_MFMA(0);
        DSB(); BAR(); DSB();
        G2_READ_A(1, 0, cur);
        if (kt + 2 < NT) G2_STAGE_B(kt + 2, 0, cur);
        DSB(); BAR(); LGKM0();
        G2_MFMA(1);
        DSB(); BAR(); DSB();
        G2_READ_A(0, 1, cur); G2_READ_B(1, cur);
        if (kt + 2 < NT) G2_STAGE_A(kt + 2, 0, cur);
        DSB(); BAR(); LGKM0();
        G2_MFMA(0);
        DSB(); BAR(); DSB();
        G2_READ_A(1, 1, cur);
        if (kt + 2 < NT) G2_STAGE_B(kt + 2, 1, cur);
        if (kt + 2 < NT) { VMW(6); } else { VMW(0); }
        DSB(); BAR(); LGKM0();
        G2_MFMA(1);
        DSB(); BAR(); DSB();
    }
#undef G2_STAGE_A
#undef G2_STAGE_B
#undef G2_READ_A
#undef G2_READ_B
#undef G2_MFMA

    #pragma unroll
    for (int m = 0; m < 8; ++m)
        #pragma unroll
        for (int n = 0; n < 4; ++n)
            #pragma unroll
            for (int r = 0; r < 4; ++r) {
                int row = mbase + wr * 128 + m * 16 + lhi * 4 + r;
                int col = nbase + wc * 64 + n * 16 + l15;
                O[(size_t)row * DMODEL + col] = acc[m][n][r];
            }
}

// ---------------------------------------------------------------------------
extern "C" void kernel_launch(void* const* d_in, const int* in_sizes, int n_in,
                              void* d_out, int out_size, void* d_ws, size_t ws_size,
                              hipStream_t stream) {
    const float* x   = (const float*)d_in[0];
    const float* Wgu = (const float*)d_in[1];
    const float* Agu = (const float*)d_in[2];
    const float* Bgu = (const float*)d_in[3];
    const float* Wd  = (const float*)d_in[4];
    const float* Ad  = (const float*)d_in[5];
    const float* Bd  = (const float*)d_in[6];
    float* out = (float*)d_out;
    char* ws = (char*)d_ws;

    bf16_t* wgut = (bf16_t*)(ws);                    // [5632][1024]
    bf16_t* wdt  = (bf16_t*)(ws + 11534336);         // [1024][2816]
    bf16_t* xb   = (bf16_t*)(ws + 17301504);         // [16384][1024]
    bf16_t* hb   = (bf16_t*)(ws + 50855936);         // [16384][2816]

    prep_weff<DMODEL, N2F><<<dim3(DMODEL / 64, N2F / 64), 256, 0, stream>>>(
        Wgu, Agu, Bgu, wgut);
    prep_weff<DFF, DMODEL><<<dim3(DFF / 64, DMODEL / 64), 256, 0, stream>>>(
        Wd, Ad, Bd, wdt);
    conv_bf16<<<(TOKENS * DMODEL / 4) / 256, 256, 0, stream>>>(
        x, xb, TOKENS * DMODEL / 4);
    gemm1<<<22 * 64, 512, 0, stream>>>(xb, wgut, hb);
    gemm2<<<4 * 64, 512, 0, stream>>>(hb, wdt, out);
}